// Round 1
// baseline (604.762 us; speedup 1.0000x reference)
//
#include <hip/hip_runtime.h>

#define NN 50000
#define EE 500000
#define FD 128
#define HD 64
#define NET 3

// ---------------- CSR build ----------------

__global__ void k_count(const int* __restrict__ d0, const int* __restrict__ d1,
                        const int* __restrict__ d2, int* __restrict__ cnt) {
    int t = blockIdx.x * 256 + threadIdx.x;
    if (t >= NET * EE) return;
    int et = t / EE;
    int e  = t - et * EE;
    const int* d = (et == 0) ? d0 : ((et == 1) ? d1 : d2);
    atomicAdd(&cnt[et * NN + d[e]], 1);
}

__global__ void k_scan(const int* __restrict__ cnt, int* __restrict__ rowptr,
                       int* __restrict__ cursor) {
    __shared__ int sh[1024];
    int et = blockIdx.x;
    const int* c = cnt + et * NN;
    int* rp = rowptr + et * (NN + 1);
    int* cu = cursor + et * NN;
    int carry = 0;
    for (int base = 0; base < NN; base += 1024) {
        int i = base + (int)threadIdx.x;
        int v = (i < NN) ? c[i] : 0;
        sh[threadIdx.x] = v;
        __syncthreads();
        for (int off = 1; off < 1024; off <<= 1) {
            int add = (threadIdx.x >= (unsigned)off) ? sh[threadIdx.x - off] : 0;
            __syncthreads();
            sh[threadIdx.x] += add;
            __syncthreads();
        }
        int inc = sh[threadIdx.x];
        int total = sh[1023];
        int excl = inc - v;
        if (i < NN) { rp[i] = carry + excl; cu[i] = carry + excl; }
        carry += total;
        __syncthreads();
    }
    if (threadIdx.x == 0) rp[NN] = carry;
}

__global__ void k_scatter(const int* __restrict__ s0, const int* __restrict__ d0,
                          const int* __restrict__ s1, const int* __restrict__ d1,
                          const int* __restrict__ s2, const int* __restrict__ d2,
                          int* __restrict__ cursor, int* __restrict__ col) {
    int t = blockIdx.x * 256 + threadIdx.x;
    if (t >= NET * EE) return;
    int et = t / EE;
    int e  = t - et * EE;
    const int* s = (et == 0) ? s0 : ((et == 1) ? s1 : s2);
    const int* d = (et == 0) ? d0 : ((et == 1) ? d1 : d2);
    int dd = d[e];
    int pos = atomicAdd(&cursor[et * NN + dd], 1);
    col[et * EE + pos] = s[e];
}

// ---------------- Layer 0 (+ fused sim head) ----------------
// One wave per node. Lane holds dims (2*lane, 2*lane+1) of the 128-dim row.

__global__ __launch_bounds__(256) void k_layer0(
    const float* __restrict__ feat, const float* __restrict__ Wm, const float* __restrict__ bm,
    const float* __restrict__ W0, const float* __restrict__ b0, const float* __restrict__ p0,
    const int* __restrict__ rowptr, const int* __restrict__ col,
    float* __restrict__ h1, float* __restrict__ simout) {
    __shared__ float w0s[FD * HD];     // 32 KiB
    __shared__ float hbuf[4][FD];      // 2 KiB
    for (int i = threadIdx.x; i < FD * HD; i += 256) w0s[i] = W0[i];

    int wave = threadIdx.x >> 6;
    int lane = threadIdx.x & 63;
    int node = (int)blockIdx.x * 4 + wave;      // NN % 4 == 0, always valid
    int d0 = lane * 2;

    const float2 fr = *(const float2*)(feat + (size_t)node * FD + d0);

    float a0 = 0.f, a1 = 0.f;
    #pragma unroll
    for (int et = 0; et < NET; ++et) {
        const int* rp = rowptr + et * (NN + 1);
        int s = rp[node], t = rp[node + 1];
        const int* cc = col + et * EE;
        float s0 = 0.f, s1 = 0.f;
        for (int base = s; base < t; base += 64) {
            int idx = base + lane;
            int my = (idx < t) ? cc[idx] : 0;        // batched index load
            int m = t - base; if (m > 64) m = 64;
            for (int j = 0; j < m; ++j) {
                int src = __shfl(my, j, 64);
                float2 v = *(const float2*)(feat + (size_t)src * FD + d0);
                s0 += v.x; s1 += v.y;
            }
        }
        int cdeg = t - s;
        float inv = 1.0f / (float)((cdeg > 0) ? cdeg : 1);
        float pe = p0[et];
        a0 += pe * tanhf(s0 * inv);
        a1 += pe * tanhf(s1 * inv);
    }
    float h0  = tanhf(a0 + fr.x);
    float h1v = tanhf(a1 + fr.y);

    // sim = tanh(feat @ Wm + bm), fused (wave shfl reduction)
    float sp0 = fr.x * Wm[d0 * 2 + 0] + fr.y * Wm[(d0 + 1) * 2 + 0];
    float sp1 = fr.x * Wm[d0 * 2 + 1] + fr.y * Wm[(d0 + 1) * 2 + 1];
    #pragma unroll
    for (int off = 32; off > 0; off >>= 1) {
        sp0 += __shfl_down(sp0, off, 64);
        sp1 += __shfl_down(sp1, off, 64);
    }
    if (lane == 0) {
        simout[node * 2 + 0] = tanhf(sp0 + bm[0]);
        simout[node * 2 + 1] = tanhf(sp1 + bm[1]);
    }

    // h @ W0 + b0  (h staged in LDS; barrier also covers the W0 staging)
    hbuf[wave][d0] = h0;
    hbuf[wave][d0 + 1] = h1v;
    __syncthreads();
    float o = b0[lane];
    #pragma unroll 16
    for (int k = 0; k < FD; ++k) o += hbuf[wave][k] * w0s[k * HD + lane];
    h1[(size_t)node * HD + lane] = o;
}

// ---------------- Layer 1 ----------------
// One wave per node; lane holds 1 of 64 hidden dims.

__global__ __launch_bounds__(256) void k_layer1(
    const float* __restrict__ h1, const float* __restrict__ W1, const float* __restrict__ b1,
    const float* __restrict__ p1, const int* __restrict__ rowptr, const int* __restrict__ col,
    float* __restrict__ out) {
    int wave = threadIdx.x >> 6;
    int lane = threadIdx.x & 63;
    int node = (int)blockIdx.x * 4 + wave;

    float hr = h1[(size_t)node * HD + lane];
    float a = 0.f;
    #pragma unroll
    for (int et = 0; et < NET; ++et) {
        const int* rp = rowptr + et * (NN + 1);
        int s = rp[node], t = rp[node + 1];
        const int* cc = col + et * EE;
        float sum = 0.f;
        for (int base = s; base < t; base += 64) {
            int idx = base + lane;
            int my = (idx < t) ? cc[idx] : 0;
            int m = t - base; if (m > 64) m = 64;
            for (int j = 0; j < m; ++j) {
                int src = __shfl(my, j, 64);
                sum += h1[(size_t)src * HD + lane];
            }
        }
        int cdeg = t - s;
        float inv = 1.0f / (float)((cdeg > 0) ? cdeg : 1);
        a += p1[et] * tanhf(sum * inv);
    }
    float g = tanhf(a + hr);

    float q0 = g * W1[lane * 2 + 0];
    float q1 = g * W1[lane * 2 + 1];
    #pragma unroll
    for (int off = 32; off > 0; off >>= 1) {
        q0 += __shfl_down(q0, off, 64);
        q1 += __shfl_down(q1, off, 64);
    }
    if (lane == 0) {
        out[node * 2 + 0] = q0 + b1[0];
        out[node * 2 + 1] = q1 + b1[1];
    }
}

// ---------------- launcher ----------------

extern "C" void kernel_launch(void* const* d_in, const int* in_sizes, int n_in,
                              void* d_out, int out_size, void* d_ws, size_t ws_size,
                              hipStream_t stream) {
    const float* feat = (const float*)d_in[0];
    const float* Wm   = (const float*)d_in[1];
    const float* bm   = (const float*)d_in[2];
    const float* W0   = (const float*)d_in[3];
    const float* b0   = (const float*)d_in[4];
    const float* W1   = (const float*)d_in[5];
    const float* b1   = (const float*)d_in[6];
    const float* p0   = (const float*)d_in[7];
    const float* p1   = (const float*)d_in[8];
    const int* src0 = (const int*)d_in[9];
    const int* dst0 = (const int*)d_in[10];
    const int* src1 = (const int*)d_in[11];
    const int* dst1 = (const int*)d_in[12];
    const int* src2 = (const int*)d_in[13];
    const int* dst2 = (const int*)d_in[14];

    char* ws = (char*)d_ws;
    // layout (16B aligned): cnt[3N] | rowptr[3(N+1)] | cursor[3N] | col[3E] | h1[N*HD]
    int*   cnt    = (int*)(ws + 0);           // 2,400,000 B
    int*   rowptr = (int*)(ws + 2400000);     //   600,016 B (padded)
    int*   cursor = (int*)(ws + 3000016);     // 2,400,000 B
    int*   col    = (int*)(ws + 5400016);     // 6,000,000 B
    float* h1     = (float*)(ws + 11400016);  // 12,800,000 B  (total ~24.2 MB)

    float* out = (float*)d_out;           // [N,2] first
    float* sim = out + (size_t)NN * 2;    // [N,2] second

    hipMemsetAsync(cnt, 0, sizeof(int) * NET * NN, stream);
    k_count<<<(NET * EE + 255) / 256, 256, 0, stream>>>(dst0, dst1, dst2, cnt);
    k_scan<<<NET, 1024, 0, stream>>>(cnt, rowptr, cursor);
    k_scatter<<<(NET * EE + 255) / 256, 256, 0, stream>>>(src0, dst0, src1, dst1, src2, dst2,
                                                          cursor, col);
    k_layer0<<<NN / 4, 256, 0, stream>>>(feat, Wm, bm, W0, b0, p0, rowptr, col, h1, sim);
    k_layer1<<<NN / 4, 256, 0, stream>>>(h1, W1, b1, p1, rowptr, col, out);
}

// Round 3
// 497.687 us; speedup vs baseline: 1.2151x; 1.2151x over previous
//
#include <hip/hip_runtime.h>

#define NN 50000
#define EE 500000
#define FD 128
#define HD 64
#define NET 3

// ---------------- CSR build ----------------

__global__ void k_count(const int* __restrict__ d0, const int* __restrict__ d1,
                        const int* __restrict__ d2, int* __restrict__ cnt) {
    int t = blockIdx.x * 256 + threadIdx.x;
    if (t >= NET * EE) return;
    int et = t / EE;
    int e  = t - et * EE;
    const int* d = (et == 0) ? d0 : ((et == 1) ? d1 : d2);
    atomicAdd(&cnt[et * NN + d[e]], 1);
}

// 3-phase scan: per-thread chunk sum -> one 1024 LDS scan -> local prefix write.
#define SCAN_CH 49   // ceil(50000/1024)
__global__ void k_scan(const int* __restrict__ cnt, int* __restrict__ rowptr,
                       int* __restrict__ cursor) {
    __shared__ int sh[1024];
    int et = blockIdx.x;
    const int* c = cnt + et * NN;
    int* rp = rowptr + et * (NN + 1);
    int* cu = cursor + et * NN;
    int t = (int)threadIdx.x;
    int beg = t * SCAN_CH;
    int end = beg + SCAN_CH; if (end > NN) end = NN;
    int sum = 0;
    for (int i = beg; i < end; ++i) sum += c[i];
    sh[t] = sum;
    __syncthreads();
    for (int off = 1; off < 1024; off <<= 1) {
        int add = (t >= off) ? sh[t - off] : 0;
        __syncthreads();
        sh[t] += add;
        __syncthreads();
    }
    int excl = sh[t] - sum;
    int total = sh[1023];
    int run = excl;
    for (int i = beg; i < end; ++i) {
        rp[i] = run; cu[i] = run; run += c[i];
    }
    if (t == 0) rp[NN] = total;
}

__global__ void k_scatter(const int* __restrict__ s0, const int* __restrict__ d0,
                          const int* __restrict__ s1, const int* __restrict__ d1,
                          const int* __restrict__ s2, const int* __restrict__ d2,
                          int* __restrict__ cursor, int* __restrict__ col) {
    int t = blockIdx.x * 256 + threadIdx.x;
    if (t >= NET * EE) return;
    int et = t / EE;
    int e  = t - et * EE;
    const int* s = (et == 0) ? s0 : ((et == 1) ? s1 : s2);
    const int* d = (et == 0) ? d0 : ((et == 1) ? d1 : d2);
    int dd = d[e];
    int pos = atomicAdd(&cursor[et * NN + dd], 1);
    col[et * EE + pos] = s[e];
}

// ---------------- Layer 0 (+ fused sim head) ----------------
// One 32-lane group per node; lane holds dims [4*l32, 4*l32+3] (float4).
// All control flow is GROUP-uniform, so every __shfl(width=32) source lane is
// active (round-2 failure was shfl across a divergent exec mask).
// 4 edges per iteration with UNCONDITIONAL loads (mask-FMA accumulate) so 4
// gathers stay in flight per group.

__global__ __launch_bounds__(256) void k_layer0(
    const float* __restrict__ feat, const float* __restrict__ Wm, const float* __restrict__ bm,
    const float* __restrict__ W0, const float* __restrict__ b0, const float* __restrict__ p0,
    const int* __restrict__ rowptr, const int* __restrict__ col,
    float* __restrict__ h1, float* __restrict__ simout) {
    __shared__ float hbuf[8][FD];      // 4 KiB
    int grp  = threadIdx.x >> 5;       // 8 nodes per block
    int l32  = threadIdx.x & 31;
    int d4   = l32 * 4;
    int node = (int)blockIdx.x * 8 + grp;   // 50000 % 8 == 0

    const float4 fr = *(const float4*)(feat + (size_t)node * FD + d4);

    float a0 = 0.f, a1 = 0.f, a2 = 0.f, a3 = 0.f;
    #pragma unroll
    for (int et = 0; et < NET; ++et) {
        const int* rp = rowptr + et * (NN + 1);
        int s = rp[node], t = rp[node + 1];
        const int* cc = col + et * EE;
        float x0 = 0.f, x1 = 0.f, x2 = 0.f, x3 = 0.f;
        for (int base = s; base < t; base += 32) {
            int idx = base + l32;
            int my = (idx < t) ? cc[idx] : 0;   // batched index load (group-wide)
            int m = t - base; if (m > 32) m = 32;
            for (int j = 0; j < m; j += 4) {
                int e0 = __shfl(my, j, 32);
                int e1 = __shfl(my, (j + 1) & 31, 32);
                int e2 = __shfl(my, (j + 2) & 31, 32);
                int e3 = __shfl(my, (j + 3) & 31, 32);
                float4 v0 = *(const float4*)(feat + (size_t)e0 * FD + d4);
                float4 v1 = *(const float4*)(feat + (size_t)e1 * FD + d4);
                float4 v2 = *(const float4*)(feat + (size_t)e2 * FD + d4);
                float4 v3 = *(const float4*)(feat + (size_t)e3 * FD + d4);
                float m1 = (j + 1 < m) ? 1.f : 0.f;
                float m2 = (j + 2 < m) ? 1.f : 0.f;
                float m3 = (j + 3 < m) ? 1.f : 0.f;
                x0 += v0.x; x1 += v0.y; x2 += v0.z; x3 += v0.w;
                x0 = fmaf(m1, v1.x, x0); x1 = fmaf(m1, v1.y, x1);
                x2 = fmaf(m1, v1.z, x2); x3 = fmaf(m1, v1.w, x3);
                x0 = fmaf(m2, v2.x, x0); x1 = fmaf(m2, v2.y, x1);
                x2 = fmaf(m2, v2.z, x2); x3 = fmaf(m2, v2.w, x3);
                x0 = fmaf(m3, v3.x, x0); x1 = fmaf(m3, v3.y, x1);
                x2 = fmaf(m3, v3.z, x2); x3 = fmaf(m3, v3.w, x3);
            }
        }
        int cdeg = t - s;
        float inv = 1.0f / (float)((cdeg > 0) ? cdeg : 1);
        float pe = p0[et];
        a0 += pe * tanhf(x0 * inv);
        a1 += pe * tanhf(x1 * inv);
        a2 += pe * tanhf(x2 * inv);
        a3 += pe * tanhf(x3 * inv);
    }
    float h0 = tanhf(a0 + fr.x);
    float hv1 = tanhf(a1 + fr.y);
    float h2 = tanhf(a2 + fr.z);
    float h3 = tanhf(a3 + fr.w);

    // sim = tanh(feat @ Wm + bm): per-lane 4-dim partial, butterfly in group.
    float sp0 = fr.x * Wm[(d4 + 0) * 2 + 0] + fr.y * Wm[(d4 + 1) * 2 + 0]
              + fr.z * Wm[(d4 + 2) * 2 + 0] + fr.w * Wm[(d4 + 3) * 2 + 0];
    float sp1 = fr.x * Wm[(d4 + 0) * 2 + 1] + fr.y * Wm[(d4 + 1) * 2 + 1]
              + fr.z * Wm[(d4 + 2) * 2 + 1] + fr.w * Wm[(d4 + 3) * 2 + 1];
    #pragma unroll
    for (int off = 16; off > 0; off >>= 1) {
        sp0 += __shfl_xor(sp0, off, 32);
        sp1 += __shfl_xor(sp1, off, 32);
    }
    if (l32 == 0) {
        simout[node * 2 + 0] = tanhf(sp0 + bm[0]);
        simout[node * 2 + 1] = tanhf(sp1 + bm[1]);
    }

    // h @ W0 + b0 : stage h row in LDS; lane computes output cols 2*l32, 2*l32+1.
    *(float4*)&hbuf[grp][d4] = make_float4(h0, hv1, h2, h3);
    __syncthreads();
    float2 o = *(const float2*)(b0 + 2 * l32);
    #pragma unroll 8
    for (int k = 0; k < FD; ++k) {
        float hk = hbuf[grp][k];                       // LDS broadcast
        float2 w = *(const float2*)(W0 + k * HD + 2 * l32);
        o.x = fmaf(hk, w.x, o.x);
        o.y = fmaf(hk, w.y, o.y);
    }
    *(float2*)(h1 + (size_t)node * HD + 2 * l32) = o;
}

// ---------------- Layer 1 ----------------
// One 16-lane group per node; lane holds dims [4*l16, 4*l16+3] of the 64-dim
// row (float4). Same uniform-group + mask-FMA structure.

__global__ __launch_bounds__(256) void k_layer1(
    const float* __restrict__ h1, const float* __restrict__ W1, const float* __restrict__ b1,
    const float* __restrict__ p1, const int* __restrict__ rowptr, const int* __restrict__ col,
    float* __restrict__ out) {
    int grp = threadIdx.x >> 4;        // 16 nodes per block
    int l16 = threadIdx.x & 15;
    int d4  = l16 * 4;
    int node = (int)blockIdx.x * 16 + grp;   // 50000 % 16 == 0

    const float4 hr = *(const float4*)(h1 + (size_t)node * HD + d4);

    float a0 = 0.f, a1 = 0.f, a2 = 0.f, a3 = 0.f;
    #pragma unroll
    for (int et = 0; et < NET; ++et) {
        const int* rp = rowptr + et * (NN + 1);
        int s = rp[node], t = rp[node + 1];
        const int* cc = col + et * EE;
        float x0 = 0.f, x1 = 0.f, x2 = 0.f, x3 = 0.f;
        for (int base = s; base < t; base += 16) {
            int idx = base + l16;
            int my = (idx < t) ? cc[idx] : 0;
            int m = t - base; if (m > 16) m = 16;
            for (int j = 0; j < m; j += 4) {
                int e0 = __shfl(my, j, 16);
                int e1 = __shfl(my, (j + 1) & 15, 16);
                int e2 = __shfl(my, (j + 2) & 15, 16);
                int e3 = __shfl(my, (j + 3) & 15, 16);
                float4 v0 = *(const float4*)(h1 + (size_t)e0 * HD + d4);
                float4 v1 = *(const float4*)(h1 + (size_t)e1 * HD + d4);
                float4 v2 = *(const float4*)(h1 + (size_t)e2 * HD + d4);
                float4 v3 = *(const float4*)(h1 + (size_t)e3 * HD + d4);
                float m1 = (j + 1 < m) ? 1.f : 0.f;
                float m2 = (j + 2 < m) ? 1.f : 0.f;
                float m3 = (j + 3 < m) ? 1.f : 0.f;
                x0 += v0.x; x1 += v0.y; x2 += v0.z; x3 += v0.w;
                x0 = fmaf(m1, v1.x, x0); x1 = fmaf(m1, v1.y, x1);
                x2 = fmaf(m1, v1.z, x2); x3 = fmaf(m1, v1.w, x3);
                x0 = fmaf(m2, v2.x, x0); x1 = fmaf(m2, v2.y, x1);
                x2 = fmaf(m2, v2.z, x2); x3 = fmaf(m2, v2.w, x3);
                x0 = fmaf(m3, v3.x, x0); x1 = fmaf(m3, v3.y, x1);
                x2 = fmaf(m3, v3.z, x2); x3 = fmaf(m3, v3.w, x3);
            }
        }
        int cdeg = t - s;
        float inv = 1.0f / (float)((cdeg > 0) ? cdeg : 1);
        float pe = p1[et];
        a0 += pe * tanhf(x0 * inv);
        a1 += pe * tanhf(x1 * inv);
        a2 += pe * tanhf(x2 * inv);
        a3 += pe * tanhf(x3 * inv);
    }
    float g0 = tanhf(a0 + hr.x);
    float g1 = tanhf(a1 + hr.y);
    float g2 = tanhf(a2 + hr.z);
    float g3 = tanhf(a3 + hr.w);

    float q0 = g0 * W1[(d4 + 0) * 2 + 0] + g1 * W1[(d4 + 1) * 2 + 0]
             + g2 * W1[(d4 + 2) * 2 + 0] + g3 * W1[(d4 + 3) * 2 + 0];
    float q1 = g0 * W1[(d4 + 0) * 2 + 1] + g1 * W1[(d4 + 1) * 2 + 1]
             + g2 * W1[(d4 + 2) * 2 + 1] + g3 * W1[(d4 + 3) * 2 + 1];
    #pragma unroll
    for (int off = 8; off > 0; off >>= 1) {
        q0 += __shfl_xor(q0, off, 16);
        q1 += __shfl_xor(q1, off, 16);
    }
    if (l16 == 0) {
        out[node * 2 + 0] = q0 + b1[0];
        out[node * 2 + 1] = q1 + b1[1];
    }
}

// ---------------- launcher ----------------

extern "C" void kernel_launch(void* const* d_in, const int* in_sizes, int n_in,
                              void* d_out, int out_size, void* d_ws, size_t ws_size,
                              hipStream_t stream) {
    const float* feat = (const float*)d_in[0];
    const float* Wm   = (const float*)d_in[1];
    const float* bm   = (const float*)d_in[2];
    const float* W0   = (const float*)d_in[3];
    const float* b0   = (const float*)d_in[4];
    const float* W1   = (const float*)d_in[5];
    const float* b1   = (const float*)d_in[6];
    const float* p0   = (const float*)d_in[7];
    const float* p1   = (const float*)d_in[8];
    const int* src0 = (const int*)d_in[9];
    const int* dst0 = (const int*)d_in[10];
    const int* src1 = (const int*)d_in[11];
    const int* dst1 = (const int*)d_in[12];
    const int* src2 = (const int*)d_in[13];
    const int* dst2 = (const int*)d_in[14];

    char* ws = (char*)d_ws;
    // layout: cnt[3N] | rowptr[3(N+1)] | cursor[3N] | col[3E] | h1[N*HD]
    int*   cnt    = (int*)(ws + 0);           // 2,400,000 B
    int*   rowptr = (int*)(ws + 2400000);     //   600,016 B (padded)
    int*   cursor = (int*)(ws + 3000016);     // 2,400,000 B
    int*   col    = (int*)(ws + 5400016);     // 6,000,000 B
    float* h1     = (float*)(ws + 11400016);  // 12,800,000 B  (total ~24.2 MB)

    float* out = (float*)d_out;           // [N,2] first
    float* sim = out + (size_t)NN * 2;    // [N,2] second

    hipMemsetAsync(cnt, 0, sizeof(int) * NET * NN, stream);
    k_count<<<(NET * EE + 255) / 256, 256, 0, stream>>>(dst0, dst1, dst2, cnt);
    k_scan<<<NET, 1024, 0, stream>>>(cnt, rowptr, cursor);
    k_scatter<<<(NET * EE + 255) / 256, 256, 0, stream>>>(src0, dst0, src1, dst1, src2, dst2,
                                                          cursor, col);
    k_layer0<<<NN / 8, 256, 0, stream>>>(feat, Wm, bm, W0, b0, p0, rowptr, col, h1, sim);
    k_layer1<<<NN / 16, 256, 0, stream>>>(h1, W1, b1, p1, rowptr, col, out);
}